// Round 1
// baseline (663.707 us; speedup 1.0000x reference)
//
#include <hip/hip_runtime.h>
#include <hip/hip_bf16.h>
#include <math.h>

// Decoder: embed -> GRU x2 -> adaptive log-softmax.
// B=256, E=512, H=1024, V=128000, tail1 N=127988 K=64.
// All heavy matmuls: bf16 MFMA 16x16x32, fp32 accum, in-kernel f32->bf16.
// d_out layout: prediction [256][128000] fp32, then new_hidden [2][256][1024].

#define BM 64
#define BN 64
#define BK 32

typedef __attribute__((ext_vector_type(8))) short frag_ab;   // 8 bf16
typedef __attribute__((ext_vector_type(4))) float frag_cd;   // 4 fp32
typedef __attribute__((ext_vector_type(4))) float floatx4;

__device__ __forceinline__ unsigned short f2bf(float f) {
    unsigned int u = __builtin_bit_cast(unsigned int, f);
    u += 0x7fffu + ((u >> 16) & 1u);   // RNE
    return (unsigned short)(u >> 16);
}

// ---------------- embedding gather: x[b][e] = emb[input[b]][e] ----------------
__global__ __launch_bounds__(256) void gather_kernel(const int* __restrict__ inp,
                                                     const float* __restrict__ emb,
                                                     float* __restrict__ x) {
    int idx = blockIdx.x * 256 + threadIdx.x;     // 256*512 = 131072
    int b = idx >> 9, e = idx & 511;
    x[idx] = emb[(size_t)inp[b] * 512 + e];
}

// ---------------- generic C[256,N] = A[256,K] @ W[N,K]^T + bias ----------------
// bt layout: both A and W rows contiguous along K. bf16 MFMA.
__global__ __launch_bounds__(256) void gemm_bt(const float* __restrict__ A,
                                               const float* __restrict__ W,
                                               const float* __restrict__ bias,
                                               float* __restrict__ C,
                                               int N, int K) {
    __shared__ unsigned short As[BM * BK];
    __shared__ unsigned short Wsh[BN * BK];
    const int m0 = blockIdx.y * BM, n0 = blockIdx.x * BN;
    const int t = threadIdx.x;
    const int lane = t & 63, wid = t >> 6;
    const int wm = wid >> 1, wn = wid & 1;
    const int quad = lane >> 4, l16 = lane & 15;
    const int lr = t >> 2;          // 0..63 tile row
    const int lc = (t & 3) * 8;     // 0/8/16/24 k-offset

    frag_cd zero4 = {0.f, 0.f, 0.f, 0.f};
    frag_cd acc[2][2] = {{zero4, zero4}, {zero4, zero4}};

    for (int k0 = 0; k0 < K; k0 += BK) {
        const float* ap = A + (size_t)(m0 + lr) * K + k0 + lc;
        floatx4 a0 = *(const floatx4*)ap;
        floatx4 a1 = *(const floatx4*)(ap + 4);
        floatx4 w0 = {0.f, 0.f, 0.f, 0.f}, w1 = {0.f, 0.f, 0.f, 0.f};
        int wr = n0 + lr;
        if (wr < N) {
            const float* wp = W + (size_t)wr * K + k0 + lc;
            w0 = *(const floatx4*)wp;
            w1 = *(const floatx4*)(wp + 4);
        }
        frag_ab apk, wpk;
#pragma unroll
        for (int i = 0; i < 4; i++) {
            apk[i]     = (short)f2bf(a0[i]);
            apk[4 + i] = (short)f2bf(a1[i]);
            wpk[i]     = (short)f2bf(w0[i]);
            wpk[4 + i] = (short)f2bf(w1[i]);
        }
        __syncthreads();
        *(frag_ab*)&As[lr * BK + lc] = apk;
        *(frag_ab*)&Wsh[lr * BK + lc] = wpk;
        __syncthreads();

        frag_ab bf[2];
#pragma unroll
        for (int tn = 0; tn < 2; tn++)
            bf[tn] = *(const frag_ab*)&Wsh[(wn * 32 + tn * 16 + l16) * BK + quad * 8];
#pragma unroll
        for (int tm = 0; tm < 2; tm++) {
            frag_ab af = *(const frag_ab*)&As[(wm * 32 + tm * 16 + l16) * BK + quad * 8];
#pragma unroll
            for (int tn = 0; tn < 2; tn++)
                acc[tm][tn] = __builtin_amdgcn_mfma_f32_16x16x32_bf16(af, bf[tn], acc[tm][tn], 0, 0, 0);
        }
    }
#pragma unroll
    for (int tm = 0; tm < 2; tm++)
#pragma unroll
        for (int tn = 0; tn < 2; tn++) {
            int col = n0 + wn * 32 + tn * 16 + l16;
            if (col < N) {
                float bv = bias ? bias[col] : 0.f;
#pragma unroll
                for (int r = 0; r < 4; r++) {
                    int row = m0 + wm * 32 + tm * 16 + quad * 4 + r;
                    C[(size_t)row * N + col] = acc[tm][tn][r] + bv;
                }
            }
        }
}

// ---------------- big tail matmul: logits[256,127988] = a[256,64] @ t1_out^T --
// Writes fp32 logits into d_out cols 12.., and per-(row, nblk) exp-sum partials.
__global__ __launch_bounds__(256) void gemm_big(const float* __restrict__ A,
                                                const float* __restrict__ W,
                                                float* __restrict__ outp,
                                                float* __restrict__ partials) {
    const int N = 127988, K = 64;
    __shared__ unsigned short As[BM * BK];
    __shared__ unsigned short Wsh[BN * BK];
    __shared__ float rowsum[BM];
    const int m0 = blockIdx.y * BM, n0 = blockIdx.x * BN;
    const int t = threadIdx.x;
    const int lane = t & 63, wid = t >> 6;
    const int wm = wid >> 1, wn = wid & 1;
    const int quad = lane >> 4, l16 = lane & 15;
    const int lr = t >> 2;
    const int lc = (t & 3) * 8;

    if (t < BM) rowsum[t] = 0.f;

    frag_cd zero4 = {0.f, 0.f, 0.f, 0.f};
    frag_cd acc[2][2] = {{zero4, zero4}, {zero4, zero4}};

    for (int k0 = 0; k0 < K; k0 += BK) {
        const float* ap = A + (size_t)(m0 + lr) * K + k0 + lc;
        floatx4 a0 = *(const floatx4*)ap;
        floatx4 a1 = *(const floatx4*)(ap + 4);
        floatx4 w0 = {0.f, 0.f, 0.f, 0.f}, w1 = {0.f, 0.f, 0.f, 0.f};
        int wr = n0 + lr;
        if (wr < N) {
            const float* wp = W + (size_t)wr * K + k0 + lc;
            w0 = *(const floatx4*)wp;
            w1 = *(const floatx4*)(wp + 4);
        }
        frag_ab apk, wpk;
#pragma unroll
        for (int i = 0; i < 4; i++) {
            apk[i]     = (short)f2bf(a0[i]);
            apk[4 + i] = (short)f2bf(a1[i]);
            wpk[i]     = (short)f2bf(w0[i]);
            wpk[4 + i] = (short)f2bf(w1[i]);
        }
        __syncthreads();
        *(frag_ab*)&As[lr * BK + lc] = apk;
        *(frag_ab*)&Wsh[lr * BK + lc] = wpk;
        __syncthreads();

        frag_ab bf[2];
#pragma unroll
        for (int tn = 0; tn < 2; tn++)
            bf[tn] = *(const frag_ab*)&Wsh[(wn * 32 + tn * 16 + l16) * BK + quad * 8];
#pragma unroll
        for (int tm = 0; tm < 2; tm++) {
            frag_ab af = *(const frag_ab*)&As[(wm * 32 + tm * 16 + l16) * BK + quad * 8];
#pragma unroll
            for (int tn = 0; tn < 2; tn++)
                acc[tm][tn] = __builtin_amdgcn_mfma_f32_16x16x32_bf16(af, bf[tn], acc[tm][tn], 0, 0, 0);
        }
    }

#pragma unroll
    for (int tm = 0; tm < 2; tm++) {
#pragma unroll
        for (int r = 0; r < 4; r++) {
            int row = m0 + wm * 32 + tm * 16 + quad * 4 + r;
            float s = 0.f;
#pragma unroll
            for (int tn = 0; tn < 2; tn++) {
                int col = n0 + wn * 32 + tn * 16 + l16;
                float v = acc[tm][tn][r];
                if (col < N) {
                    s += __expf(v);
                    outp[(size_t)row * 128000 + 12 + col] = v;
                }
            }
            s += __shfl_xor(s, 1);
            s += __shfl_xor(s, 2);
            s += __shfl_xor(s, 4);
            s += __shfl_xor(s, 8);
            if (l16 == 0) atomicAdd(&rowsum[wm * 32 + tm * 16 + quad * 4 + r], s);
        }
    }
    __syncthreads();
    if (t < BM) partials[(size_t)(m0 + t) * 2048 + blockIdx.x] = rowsum[t];
}

// ---------------- GRU gate combine ----------------
__global__ __launch_bounds__(256) void gru_gate(const float* __restrict__ gi,
                                                const float* __restrict__ gh,
                                                const float* __restrict__ hprev,
                                                float* __restrict__ hout) {
    int idx = blockIdx.x * 256 + threadIdx.x;   // 256*1024
    int b = idx >> 10, j = idx & 1023;
    const float* gib = gi + (size_t)b * 3072;
    const float* ghb = gh + (size_t)b * 3072;
    float ir = gib[j], iz = gib[1024 + j], in_ = gib[2048 + j];
    float hr = ghb[j], hz = ghb[1024 + j], hn = ghb[2048 + j];
    float r = 1.f / (1.f + __expf(-(ir + hr)));
    float z = 1.f / (1.f + __expf(-(iz + hz)));
    float n = tanhf(in_ + r * hn);
    hout[idx] = (1.f - z) * n + z * hprev[idx];
}

// ---------------- head: logits[12] -> log_softmax, write cols 0..9 -----------
__global__ __launch_bounds__(256) void head_kernel(const float* __restrict__ h1,
                                                   const float* __restrict__ head_w,
                                                   float* __restrict__ head_lp,
                                                   float* __restrict__ outp) {
    int b = blockIdx.x, t = threadIdx.x;
    __shared__ float hrow[1024];
    __shared__ float accw[12][4];
    __shared__ float lg[12];
    for (int k = t; k < 1024; k += 256) hrow[k] = h1[(size_t)b * 1024 + k];
    __syncthreads();
    for (int o = 0; o < 12; o++) {
        float s = 0.f;
        for (int k = t; k < 1024; k += 256) s += hrow[k] * head_w[(size_t)o * 1024 + k];
        s += __shfl_xor(s, 1);  s += __shfl_xor(s, 2);  s += __shfl_xor(s, 4);
        s += __shfl_xor(s, 8);  s += __shfl_xor(s, 16); s += __shfl_xor(s, 32);
        if ((t & 63) == 0) accw[o][t >> 6] = s;
    }
    __syncthreads();
    if (t < 12) lg[t] = accw[t][0] + accw[t][1] + accw[t][2] + accw[t][3];
    __syncthreads();
    if (t == 0) {
        float m = lg[0];
        for (int i = 1; i < 12; i++) m = fmaxf(m, lg[i]);
        float se = 0.f;
        for (int i = 0; i < 12; i++) se += __expf(lg[i] - m);
        float lse = m + logf(se);
        for (int i = 0; i < 12; i++) {
            float v = lg[i] - lse;
            head_lp[b * 12 + i] = v;
            if (i < 10) outp[(size_t)b * 128000 + i] = v;
        }
    }
}

// ---------------- tail-0 cluster: c0 = log_softmax(p @ t0_out^T) + head[10] --
__global__ __launch_bounds__(256) void c0_kernel(const float* __restrict__ p,
                                                 const float* __restrict__ t0_out,
                                                 const float* __restrict__ head_lp,
                                                 float* __restrict__ outp) {
    int b = blockIdx.x, t = threadIdx.x;
    __shared__ float a0[4], a1[4];
    float pv = p[(size_t)b * 256 + t];
    float s0 = pv * t0_out[t];
    float s1 = pv * t0_out[256 + t];
    s0 += __shfl_xor(s0, 1);  s0 += __shfl_xor(s0, 2);  s0 += __shfl_xor(s0, 4);
    s0 += __shfl_xor(s0, 8);  s0 += __shfl_xor(s0, 16); s0 += __shfl_xor(s0, 32);
    s1 += __shfl_xor(s1, 1);  s1 += __shfl_xor(s1, 2);  s1 += __shfl_xor(s1, 4);
    s1 += __shfl_xor(s1, 8);  s1 += __shfl_xor(s1, 16); s1 += __shfl_xor(s1, 32);
    if ((t & 63) == 0) { a0[t >> 6] = s0; a1[t >> 6] = s1; }
    __syncthreads();
    if (t == 0) {
        float l0 = a0[0] + a0[1] + a0[2] + a0[3];
        float l1 = a1[0] + a1[1] + a1[2] + a1[3];
        float m = fmaxf(l0, l1);
        float lse = m + logf(__expf(l0 - m) + __expf(l1 - m));
        float hp = head_lp[b * 12 + 10];
        outp[(size_t)b * 128000 + 10] = l0 - lse + hp;
        outp[(size_t)b * 128000 + 11] = l1 - lse + hp;
    }
}

// ---------------- reduce partials -> rowOff[b] = head[11] - log(sum) ---------
__global__ __launch_bounds__(256) void reduce_kernel(const float* __restrict__ partials,
                                                     const float* __restrict__ head_lp,
                                                     float* __restrict__ rowOff) {
    int b = blockIdx.x, t = threadIdx.x;
    __shared__ float a[4];
    float s = 0.f;
    for (int k = t; k < 2000; k += 256) s += partials[(size_t)b * 2048 + k];
    s += __shfl_xor(s, 1);  s += __shfl_xor(s, 2);  s += __shfl_xor(s, 4);
    s += __shfl_xor(s, 8);  s += __shfl_xor(s, 16); s += __shfl_xor(s, 32);
    if ((t & 63) == 0) a[t >> 6] = s;
    __syncthreads();
    if (t == 0) {
        float S = a[0] + a[1] + a[2] + a[3];
        rowOff[b] = head_lp[b * 12 + 11] - logf(S);
    }
}

// ---------------- final in-place add of rowOff over c1 region ----------------
__global__ __launch_bounds__(256) void final_kernel(float* __restrict__ outp,
                                                    const float* __restrict__ rowOff) {
    int b = blockIdx.y;
    int i = blockIdx.x * 256 + threadIdx.x;      // 0..31996 float4s (127988/4)
    if (i < 31997) {
        float ro = rowOff[b];
        floatx4* p = (floatx4*)(outp + (size_t)b * 128000 + 12) + i;
        floatx4 v = *p;
        v[0] += ro; v[1] += ro; v[2] += ro; v[3] += ro;
        *p = v;
    }
}

extern "C" void kernel_launch(void* const* d_in, const int* in_sizes, int n_in,
                              void* d_out, int out_size, void* d_ws, size_t ws_size,
                              hipStream_t stream) {
    const int*   input  = (const int*)d_in[0];
    const float* hidden = (const float*)d_in[1];
    // d_in[2] = start_state (unused by reference)
    const float* emb    = (const float*)d_in[3];
    const float* w_ih0  = (const float*)d_in[4];
    const float* w_hh0  = (const float*)d_in[5];
    const float* b_ih0  = (const float*)d_in[6];
    const float* b_hh0  = (const float*)d_in[7];
    const float* w_ih1  = (const float*)d_in[8];
    const float* w_hh1  = (const float*)d_in[9];
    const float* b_ih1  = (const float*)d_in[10];
    const float* b_hh1  = (const float*)d_in[11];
    const float* head_w = (const float*)d_in[12];
    const float* t0_proj = (const float*)d_in[13];
    const float* t0_out  = (const float*)d_in[14];
    const float* t1_proj = (const float*)d_in[15];
    const float* t1_out  = (const float*)d_in[16];

    float* outp = (float*)d_out;
    float* ws   = (float*)d_ws;

    float* x        = ws;                    // 131072
    float* gi       = x + 131072;            // 786432
    float* gh       = gi + 786432;           // 786432
    float* pbuf     = gh + 786432;           // 65536
    float* abuf     = pbuf + 65536;          // 16384
    float* hlp      = abuf + 16384;          // 3072
    float* rowOff   = hlp + 3072;            // 256
    float* partials = rowOff + 256;          // 256*2048

    float* h0 = outp + 32768000;             // new_hidden[0]
    float* h1 = h0 + 262144;                 // new_hidden[1]

    gather_kernel<<<512, 256, 0, stream>>>(input, emb, x);
    gemm_bt<<<dim3(48, 4), 256, 0, stream>>>(x, w_ih0, b_ih0, gi, 3072, 512);
    gemm_bt<<<dim3(48, 4), 256, 0, stream>>>(hidden, w_hh0, b_hh0, gh, 3072, 1024);
    gru_gate<<<1024, 256, 0, stream>>>(gi, gh, hidden, h0);
    gemm_bt<<<dim3(48, 4), 256, 0, stream>>>(h0, w_ih1, b_ih1, gi, 3072, 1024);
    gemm_bt<<<dim3(48, 4), 256, 0, stream>>>(hidden + 262144, w_hh1, b_hh1, gh, 3072, 1024);
    gru_gate<<<1024, 256, 0, stream>>>(gi, gh, hidden + 262144, h1);
    head_kernel<<<256, 256, 0, stream>>>(h1, head_w, hlp, outp);
    gemm_bt<<<dim3(4, 4), 256, 0, stream>>>(h1, t0_proj, nullptr, pbuf, 256, 1024);
    c0_kernel<<<256, 256, 0, stream>>>(pbuf, t0_out, hlp, outp);
    gemm_bt<<<dim3(1, 4), 256, 0, stream>>>(h1, t1_proj, nullptr, abuf, 64, 1024);
    gemm_big<<<dim3(2000, 4), 256, 0, stream>>>(abuf, t1_out, outp, partials);
    reduce_kernel<<<256, 256, 0, stream>>>(partials, hlp, rowOff);
    final_kernel<<<dim3(125, 256), 256, 0, stream>>>(outp, rowOff);
}

// Round 2
// 524.205 us; speedup vs baseline: 1.2661x; 1.2661x over previous
//
#include <hip/hip_runtime.h>
#include <hip/hip_bf16.h>
#include <math.h>

// Decoder: embed -> GRU x2 -> adaptive log-softmax. B=256, E=512, H=1024,
// V=128000, tail1 N=127988 K=64.
// R2 structure: 9 launches.
//  1. gru_gemm L0   (gather fused, gi/gh batched via z, split-K 2 -> 768 blocks)
//  2. gru_gate L0   (bias adds moved here)
//  3. gru_gemm L1
//  4. gru_gate L1
//  5. small_gemm    (head_w + t0_proj + t1_proj as one N=332 gemm, split-K 2)
//  6. postproc      (head log-softmax, c0 cluster, abuf extract)
//  7. big_pass1     (tail logits -> exp-sums only, nothing materialized)
//  8. reduce        (rowOff[b] = head_lp[11] - log(sum))
//  9. big_pass2     (recompute tail logits, write final = v + rowOff) -- tail
//     matmul is 4.2 GFLOP; recompute beats a 262 MB logit round-trip.

#define BM 64
#define BN 64
#define BK 32

typedef __attribute__((ext_vector_type(8))) short frag_ab;   // 8 bf16
typedef __attribute__((ext_vector_type(4))) float frag_cd;   // 4 fp32
typedef __attribute__((ext_vector_type(4))) float floatx4;

__device__ __forceinline__ unsigned short f2bf(float f) {
    unsigned int u = __builtin_bit_cast(unsigned int, f);
    u += 0x7fffu + ((u >> 16) & 1u);   // RNE
    return (unsigned short)(u >> 16);
}

// ---------------------------------------------------------------------------
// GRU gemm: C[z] = A_side[256,K] @ W_side[3072,K]^T, z = side*2 + khalf.
// side 0: A_ih (optionally gathered from emb via idx), W_ih, K=Kih
// side 1: A_hh, W_hh, K=Khh
// Output: outbase + z*786432, partial over its K-half.
// ---------------------------------------------------------------------------
__global__ __launch_bounds__(256) void gru_gemm(const int* __restrict__ idx,
                                                const float* __restrict__ A_ih,
                                                const float* __restrict__ A_hh,
                                                const float* __restrict__ W_ih,
                                                const float* __restrict__ W_hh,
                                                float* __restrict__ outbase,
                                                int Kih, int Khh) {
    const int z = blockIdx.z;
    const int side = z >> 1, half = z & 1;
    const int K = side ? Khh : Kih;
    const int Kh = K >> 1;
    const float* A = side ? A_hh : A_ih;
    const float* W = side ? W_hh : W_ih;
    float* C = outbase + (size_t)z * 786432;

    __shared__ unsigned short As[BM * BK];
    __shared__ unsigned short Wsh[BN * BK];
    const int m0 = blockIdx.y * BM, n0 = blockIdx.x * BN;
    const int t = threadIdx.x;
    const int lane = t & 63, wid = t >> 6;
    const int wm = wid >> 1, wn = wid & 1;
    const int quad = lane >> 4, l16 = lane & 15;
    const int lr = t >> 2;          // 0..63 tile row
    const int lc = (t & 3) * 8;     // 0/8/16/24 k-offset

    const int m = m0 + lr;
    const float* arow = (side == 0 && idx) ? A + (size_t)idx[m] * K
                                           : A + (size_t)m * K;
    arow += (size_t)half * Kh + lc;
    const float* wrow = W + (size_t)(n0 + lr) * K + (size_t)half * Kh + lc;

    frag_cd zero4 = {0.f, 0.f, 0.f, 0.f};
    frag_cd acc[2][2] = {{zero4, zero4}, {zero4, zero4}};

    for (int k0 = 0; k0 < Kh; k0 += BK) {
        floatx4 a0 = *(const floatx4*)(arow + k0);
        floatx4 a1 = *(const floatx4*)(arow + k0 + 4);
        floatx4 w0 = *(const floatx4*)(wrow + k0);
        floatx4 w1 = *(const floatx4*)(wrow + k0 + 4);
        frag_ab apk, wpk;
#pragma unroll
        for (int i = 0; i < 4; i++) {
            apk[i]     = (short)f2bf(a0[i]);
            apk[4 + i] = (short)f2bf(a1[i]);
            wpk[i]     = (short)f2bf(w0[i]);
            wpk[4 + i] = (short)f2bf(w1[i]);
        }
        __syncthreads();
        *(frag_ab*)&As[lr * BK + lc] = apk;
        *(frag_ab*)&Wsh[lr * BK + lc] = wpk;
        __syncthreads();

        frag_ab bfr[2];
#pragma unroll
        for (int tn = 0; tn < 2; tn++)
            bfr[tn] = *(const frag_ab*)&Wsh[(wn * 32 + tn * 16 + l16) * BK + quad * 8];
#pragma unroll
        for (int tm = 0; tm < 2; tm++) {
            frag_ab af = *(const frag_ab*)&As[(wm * 32 + tm * 16 + l16) * BK + quad * 8];
#pragma unroll
            for (int tn = 0; tn < 2; tn++)
                acc[tm][tn] = __builtin_amdgcn_mfma_f32_16x16x32_bf16(af, bfr[tn], acc[tm][tn], 0, 0, 0);
        }
    }
#pragma unroll
    for (int tm = 0; tm < 2; tm++)
#pragma unroll
        for (int tn = 0; tn < 2; tn++) {
            int col = n0 + wn * 32 + tn * 16 + l16;
#pragma unroll
            for (int r = 0; r < 4; r++) {
                int row = m0 + wm * 32 + tm * 16 + quad * 4 + r;
                C[(size_t)row * 3072 + col] = acc[tm][tn][r];
            }
        }
}

// ---------------------------------------------------------------------------
// GRU gate combine; sums split-K partials and adds biases here.
// P layout: gi0, gi1, gh0, gh1 each 786432 floats.
// ---------------------------------------------------------------------------
__global__ __launch_bounds__(256) void gru_gate(const float* __restrict__ P,
                                                const float* __restrict__ b_ih,
                                                const float* __restrict__ b_hh,
                                                const float* __restrict__ hprev,
                                                float* __restrict__ hout) {
    int idx = blockIdx.x * 256 + threadIdx.x;   // 256*1024
    int b = idx >> 10, j = idx & 1023;
    const float* g = P + (size_t)b * 3072 + j;
    float ir  = g[0]    + g[786432]        + b_ih[j];
    float iz  = g[1024] + g[786432 + 1024] + b_ih[1024 + j];
    float in_ = g[2048] + g[786432 + 2048] + b_ih[2048 + j];
    const float* gh = g + 2 * 786432;
    float hr  = gh[0]    + gh[786432]        + b_hh[j];
    float hz  = gh[1024] + gh[786432 + 1024] + b_hh[1024 + j];
    float hn  = gh[2048] + gh[786432 + 2048] + b_hh[2048 + j];
    float r = 1.f / (1.f + __expf(-(ir + hr)));
    float z = 1.f / (1.f + __expf(-(iz + hz)));
    float n = tanhf(in_ + r * hn);
    hout[idx] = (1.f - z) * n + z * hprev[idx];
}

// ---------------------------------------------------------------------------
// Small combined gemm: C[256, 332(+pad 384)] = h1 @ [head_w; t0_proj; t1_proj]^T
// split-K 2 (z = half). Output c_p + half*98304, row stride 384.
// ---------------------------------------------------------------------------
__global__ __launch_bounds__(256) void small_gemm(const float* __restrict__ A,
                                                  const float* __restrict__ head_w,
                                                  const float* __restrict__ t0_proj,
                                                  const float* __restrict__ t1_proj,
                                                  float* __restrict__ c_p) {
    const int K = 1024, Kh = 512;
    const int half = blockIdx.z;
    float* C = c_p + (size_t)half * 98304;

    __shared__ unsigned short As[BM * BK];
    __shared__ unsigned short Wsh[BN * BK];
    const int m0 = blockIdx.y * BM, n0 = blockIdx.x * BN;
    const int t = threadIdx.x;
    const int lane = t & 63, wid = t >> 6;
    const int wm = wid >> 1, wn = wid & 1;
    const int quad = lane >> 4, l16 = lane & 15;
    const int lr = t >> 2;
    const int lc = (t & 3) * 8;

    const float* arow = A + (size_t)(m0 + lr) * K + (size_t)half * Kh + lc;
    int wr = n0 + lr;
    const float* wrow;
    if (wr < 12)       wrow = head_w  + (size_t)wr * K;
    else if (wr < 268) wrow = t0_proj + (size_t)(wr - 12) * K;
    else if (wr < 332) wrow = t1_proj + (size_t)(wr - 268) * K;
    else               wrow = nullptr;
    if (wrow) wrow += (size_t)half * Kh + lc;

    frag_cd zero4 = {0.f, 0.f, 0.f, 0.f};
    frag_cd acc[2][2] = {{zero4, zero4}, {zero4, zero4}};

    for (int k0 = 0; k0 < Kh; k0 += BK) {
        floatx4 a0 = *(const floatx4*)(arow + k0);
        floatx4 a1 = *(const floatx4*)(arow + k0 + 4);
        floatx4 w0 = {0.f, 0.f, 0.f, 0.f}, w1 = {0.f, 0.f, 0.f, 0.f};
        if (wrow) {
            w0 = *(const floatx4*)(wrow + k0);
            w1 = *(const floatx4*)(wrow + k0 + 4);
        }
        frag_ab apk, wpk;
#pragma unroll
        for (int i = 0; i < 4; i++) {
            apk[i]     = (short)f2bf(a0[i]);
            apk[4 + i] = (short)f2bf(a1[i]);
            wpk[i]     = (short)f2bf(w0[i]);
            wpk[4 + i] = (short)f2bf(w1[i]);
        }
        __syncthreads();
        *(frag_ab*)&As[lr * BK + lc] = apk;
        *(frag_ab*)&Wsh[lr * BK + lc] = wpk;
        __syncthreads();

        frag_ab bfr[2];
#pragma unroll
        for (int tn = 0; tn < 2; tn++)
            bfr[tn] = *(const frag_ab*)&Wsh[(wn * 32 + tn * 16 + l16) * BK + quad * 8];
#pragma unroll
        for (int tm = 0; tm < 2; tm++) {
            frag_ab af = *(const frag_ab*)&As[(wm * 32 + tm * 16 + l16) * BK + quad * 8];
#pragma unroll
            for (int tn = 0; tn < 2; tn++)
                acc[tm][tn] = __builtin_amdgcn_mfma_f32_16x16x32_bf16(af, bfr[tn], acc[tm][tn], 0, 0, 0);
        }
    }
#pragma unroll
    for (int tm = 0; tm < 2; tm++)
#pragma unroll
        for (int tn = 0; tn < 2; tn++) {
            int col = n0 + wn * 32 + tn * 16 + l16;   // < 384 always
#pragma unroll
            for (int r = 0; r < 4; r++) {
                int row = m0 + wm * 32 + tm * 16 + quad * 4 + r;
                C[(size_t)row * 384 + col] = acc[tm][tn][r];
            }
        }
}

// ---------------------------------------------------------------------------
// postproc: per b — sum split-K halves; head log-softmax (cols 0..9);
// c0 cluster (cols 10,11); extract abuf = t1 projection; stash head_lp[11].
// ---------------------------------------------------------------------------
__global__ __launch_bounds__(256) void postproc(const float* __restrict__ c_p,
                                                const float* __restrict__ t0_out,
                                                float* __restrict__ outp,
                                                float* __restrict__ abuf,
                                                float* __restrict__ h11buf) {
    int b = blockIdx.x, t = threadIdx.x;
    __shared__ float c[332];
    __shared__ float a0s[4], a1s[4];
    __shared__ float sh_lse;
    for (int j = t; j < 332; j += 256)
        c[j] = c_p[(size_t)b * 384 + j] + c_p[98304 + (size_t)b * 384 + j];
    __syncthreads();
    if (t == 0) {
        float m = c[0];
        for (int i = 1; i < 12; i++) m = fmaxf(m, c[i]);
        float se = 0.f;
        for (int i = 0; i < 12; i++) se += __expf(c[i] - m);
        sh_lse = m + logf(se);
    }
    __syncthreads();
    if (t < 10) outp[(size_t)b * 128000 + t] = c[t] - sh_lse;
    if (t < 64) abuf[(size_t)b * 64 + t] = c[268 + t];

    float pv = c[12 + t];
    float s0 = pv * t0_out[t];
    float s1 = pv * t0_out[256 + t];
    s0 += __shfl_xor(s0, 1);  s0 += __shfl_xor(s0, 2);  s0 += __shfl_xor(s0, 4);
    s0 += __shfl_xor(s0, 8);  s0 += __shfl_xor(s0, 16); s0 += __shfl_xor(s0, 32);
    s1 += __shfl_xor(s1, 1);  s1 += __shfl_xor(s1, 2);  s1 += __shfl_xor(s1, 4);
    s1 += __shfl_xor(s1, 8);  s1 += __shfl_xor(s1, 16); s1 += __shfl_xor(s1, 32);
    if ((t & 63) == 0) { a0s[t >> 6] = s0; a1s[t >> 6] = s1; }
    __syncthreads();
    if (t == 0) {
        float l0 = a0s[0] + a0s[1] + a0s[2] + a0s[3];
        float l1 = a1s[0] + a1s[1] + a1s[2] + a1s[3];
        float m = fmaxf(l0, l1);
        float lse2 = m + logf(__expf(l0 - m) + __expf(l1 - m));
        float hp = c[10] - sh_lse;
        outp[(size_t)b * 128000 + 10] = l0 - lse2 + hp;
        outp[(size_t)b * 128000 + 11] = l1 - lse2 + hp;
        h11buf[b] = c[11] - sh_lse;
    }
}

// ---------------------------------------------------------------------------
// big tail matmul pass 1: exp-sums only (no logits materialized).
// ---------------------------------------------------------------------------
__global__ __launch_bounds__(256) void big_pass1(const float* __restrict__ A,
                                                 const float* __restrict__ W,
                                                 float* __restrict__ partials) {
    const int N = 127988, K = 64;
    __shared__ unsigned short As[BM * BK];
    __shared__ unsigned short Wsh[BN * BK];
    __shared__ float rowsum[BM];
    const int m0 = blockIdx.y * BM, n0 = blockIdx.x * BN;
    const int t = threadIdx.x;
    const int lane = t & 63, wid = t >> 6;
    const int wm = wid >> 1, wn = wid & 1;
    const int quad = lane >> 4, l16 = lane & 15;
    const int lr = t >> 2;
    const int lc = (t & 3) * 8;

    if (t < BM) rowsum[t] = 0.f;

    const float* arow = A + (size_t)(m0 + lr) * K + lc;
    int wr = n0 + lr;
    const float* wrow = (wr < N) ? W + (size_t)wr * K + lc : nullptr;

    frag_cd zero4 = {0.f, 0.f, 0.f, 0.f};
    frag_cd acc[2][2] = {{zero4, zero4}, {zero4, zero4}};

    for (int k0 = 0; k0 < K; k0 += BK) {
        floatx4 a0 = *(const floatx4*)(arow + k0);
        floatx4 a1 = *(const floatx4*)(arow + k0 + 4);
        floatx4 w0 = {0.f, 0.f, 0.f, 0.f}, w1 = {0.f, 0.f, 0.f, 0.f};
        if (wrow) {
            w0 = *(const floatx4*)(wrow + k0);
            w1 = *(const floatx4*)(wrow + k0 + 4);
        }
        frag_ab apk, wpk;
#pragma unroll
        for (int i = 0; i < 4; i++) {
            apk[i]     = (short)f2bf(a0[i]);
            apk[4 + i] = (short)f2bf(a1[i]);
            wpk[i]     = (short)f2bf(w0[i]);
            wpk[4 + i] = (short)f2bf(w1[i]);
        }
        __syncthreads();
        *(frag_ab*)&As[lr * BK + lc] = apk;
        *(frag_ab*)&Wsh[lr * BK + lc] = wpk;
        __syncthreads();

        frag_ab bfr[2];
#pragma unroll
        for (int tn = 0; tn < 2; tn++)
            bfr[tn] = *(const frag_ab*)&Wsh[(wn * 32 + tn * 16 + l16) * BK + quad * 8];
#pragma unroll
        for (int tm = 0; tm < 2; tm++) {
            frag_ab af = *(const frag_ab*)&As[(wm * 32 + tm * 16 + l16) * BK + quad * 8];
#pragma unroll
            for (int tn = 0; tn < 2; tn++)
                acc[tm][tn] = __builtin_amdgcn_mfma_f32_16x16x32_bf16(af, bfr[tn], acc[tm][tn], 0, 0, 0);
        }
    }

#pragma unroll
    for (int tm = 0; tm < 2; tm++) {
#pragma unroll
        for (int r = 0; r < 4; r++) {
            float s = 0.f;
#pragma unroll
            for (int tn = 0; tn < 2; tn++) {
                int col = n0 + wn * 32 + tn * 16 + l16;
                if (col < N) s += __expf(acc[tm][tn][r]);
            }
            s += __shfl_xor(s, 1);
            s += __shfl_xor(s, 2);
            s += __shfl_xor(s, 4);
            s += __shfl_xor(s, 8);
            if (l16 == 0) atomicAdd(&rowsum[wm * 32 + tm * 16 + quad * 4 + r], s);
        }
    }
    __syncthreads();
    if (t < BM) partials[(size_t)(m0 + t) * 2048 + blockIdx.x] = rowsum[t];
}

// ---------------------------------------------------------------------------
// reduce partials -> rowOff[b] = head_lp[11] - log(sum)
// ---------------------------------------------------------------------------
__global__ __launch_bounds__(256) void reduce_kernel(const float* __restrict__ partials,
                                                     const float* __restrict__ h11buf,
                                                     float* __restrict__ rowOff) {
    int b = blockIdx.x, t = threadIdx.x;
    __shared__ float a[4];
    float s = 0.f;
    for (int k = t; k < 2000; k += 256) s += partials[(size_t)b * 2048 + k];
    s += __shfl_xor(s, 1);  s += __shfl_xor(s, 2);  s += __shfl_xor(s, 4);
    s += __shfl_xor(s, 8);  s += __shfl_xor(s, 16); s += __shfl_xor(s, 32);
    if ((t & 63) == 0) a[t >> 6] = s;
    __syncthreads();
    if (t == 0) rowOff[b] = h11buf[b] - logf(a[0] + a[1] + a[2] + a[3]);
}

// ---------------------------------------------------------------------------
// big tail matmul pass 2: recompute, write final = v + rowOff[row].
// ---------------------------------------------------------------------------
__global__ __launch_bounds__(256) void big_pass2(const float* __restrict__ A,
                                                 const float* __restrict__ W,
                                                 const float* __restrict__ rowOff,
                                                 float* __restrict__ outp) {
    const int N = 127988, K = 64;
    __shared__ unsigned short As[BM * BK];
    __shared__ unsigned short Wsh[BN * BK];
    __shared__ float ro[BM];
    const int m0 = blockIdx.y * BM, n0 = blockIdx.x * BN;
    const int t = threadIdx.x;
    const int lane = t & 63, wid = t >> 6;
    const int wm = wid >> 1, wn = wid & 1;
    const int quad = lane >> 4, l16 = lane & 15;
    const int lr = t >> 2;
    const int lc = (t & 3) * 8;

    if (t < BM) ro[t] = rowOff[m0 + t];

    const float* arow = A + (size_t)(m0 + lr) * K + lc;
    int wr = n0 + lr;
    const float* wrow = (wr < N) ? W + (size_t)wr * K + lc : nullptr;

    frag_cd zero4 = {0.f, 0.f, 0.f, 0.f};
    frag_cd acc[2][2] = {{zero4, zero4}, {zero4, zero4}};

    for (int k0 = 0; k0 < K; k0 += BK) {
        floatx4 a0 = *(const floatx4*)(arow + k0);
        floatx4 a1 = *(const floatx4*)(arow + k0 + 4);
        floatx4 w0 = {0.f, 0.f, 0.f, 0.f}, w1 = {0.f, 0.f, 0.f, 0.f};
        if (wrow) {
            w0 = *(const floatx4*)(wrow + k0);
            w1 = *(const floatx4*)(wrow + k0 + 4);
        }
        frag_ab apk, wpk;
#pragma unroll
        for (int i = 0; i < 4; i++) {
            apk[i]     = (short)f2bf(a0[i]);
            apk[4 + i] = (short)f2bf(a1[i]);
            wpk[i]     = (short)f2bf(w0[i]);
            wpk[4 + i] = (short)f2bf(w1[i]);
        }
        __syncthreads();
        *(frag_ab*)&As[lr * BK + lc] = apk;
        *(frag_ab*)&Wsh[lr * BK + lc] = wpk;
        __syncthreads();

        frag_ab bfr[2];
#pragma unroll
        for (int tn = 0; tn < 2; tn++)
            bfr[tn] = *(const frag_ab*)&Wsh[(wn * 32 + tn * 16 + l16) * BK + quad * 8];
#pragma unroll
        for (int tm = 0; tm < 2; tm++) {
            frag_ab af = *(const frag_ab*)&As[(wm * 32 + tm * 16 + l16) * BK + quad * 8];
#pragma unroll
            for (int tn = 0; tn < 2; tn++)
                acc[tm][tn] = __builtin_amdgcn_mfma_f32_16x16x32_bf16(af, bfr[tn], acc[tm][tn], 0, 0, 0);
        }
    }

#pragma unroll
    for (int tm = 0; tm < 2; tm++)
#pragma unroll
        for (int tn = 0; tn < 2; tn++) {
            int col = n0 + wn * 32 + tn * 16 + l16;
            if (col < N) {
#pragma unroll
                for (int r = 0; r < 4; r++) {
                    int rl = wm * 32 + tm * 16 + quad * 4 + r;
                    outp[(size_t)(m0 + rl) * 128000 + 12 + col] = acc[tm][tn][r] + ro[rl];
                }
            }
        }
}

extern "C" void kernel_launch(void* const* d_in, const int* in_sizes, int n_in,
                              void* d_out, int out_size, void* d_ws, size_t ws_size,
                              hipStream_t stream) {
    const int*   input  = (const int*)d_in[0];
    const float* hidden = (const float*)d_in[1];
    const float* emb    = (const float*)d_in[3];
    const float* w_ih0  = (const float*)d_in[4];
    const float* w_hh0  = (const float*)d_in[5];
    const float* b_ih0  = (const float*)d_in[6];
    const float* b_hh0  = (const float*)d_in[7];
    const float* w_ih1  = (const float*)d_in[8];
    const float* w_hh1  = (const float*)d_in[9];
    const float* b_ih1  = (const float*)d_in[10];
    const float* b_hh1  = (const float*)d_in[11];
    const float* head_w = (const float*)d_in[12];
    const float* t0_proj = (const float*)d_in[13];
    const float* t0_out  = (const float*)d_in[14];
    const float* t1_proj = (const float*)d_in[15];
    const float* t1_out  = (const float*)d_in[16];

    float* outp = (float*)d_out;
    float* ws   = (float*)d_ws;

    float* gruws    = ws;                       // 4 * 786432
    float* c_p      = gruws + 4 * 786432;       // 2 * 98304
    float* abuf     = c_p + 2 * 98304;          // 16384
    float* h11buf   = abuf + 16384;             // 256
    float* rowOff   = h11buf + 256;             // 256
    float* partials = rowOff + 256;             // 256 * 2048

    float* h0 = outp + 32768000;                // new_hidden[0]
    float* h1 = h0 + 262144;                    // new_hidden[1]

    gru_gemm<<<dim3(48, 4, 4), 256, 0, stream>>>(input, emb, hidden,
                                                 w_ih0, w_hh0, gruws, 512, 1024);
    gru_gate<<<1024, 256, 0, stream>>>(gruws, b_ih0, b_hh0, hidden, h0);
    gru_gemm<<<dim3(48, 4, 4), 256, 0, stream>>>(nullptr, h0, hidden + 262144,
                                                 w_ih1, w_hh1, gruws, 1024, 1024);
    gru_gate<<<1024, 256, 0, stream>>>(gruws, b_ih1, b_hh1, hidden + 262144, h1);
    small_gemm<<<dim3(6, 4, 2), 256, 0, stream>>>(h1, head_w, t0_proj, t1_proj, c_p);
    postproc<<<256, 256, 0, stream>>>(c_p, t0_out, outp, abuf, h11buf);
    big_pass1<<<dim3(2000, 4), 256, 0, stream>>>(abuf, t1_out, partials);
    reduce_kernel<<<256, 256, 0, stream>>>(partials, h11buf, rowOff);
    big_pass2<<<dim3(2000, 4), 256, 0, stream>>>(abuf, t1_out, rowOff, outp);
}